// Round 2
// baseline (922.436 us; speedup 1.0000x reference)
//
#include <hip/hip_runtime.h>

// Neural stack, decoupled: (1) sim kernel — 128 lanes (16/block x 8 blocks),
// each lane runs one batch's full T-step stack sim with a full-depth per-lane
// LDS stack (stride 513 to spread banks) and emits compacted (coeff, idx)
// lists to global ws; (2) read kernel — one wave per (t,b) output row, float4
// gather of v rows weighted by the list. Removes the per-step barrier and the
// gather from the serial critical path entirely.

#define TT 512
#define BB 128
#define EE 256
#define W  12        // register window depth for pop/read fast path
#define K  32        // list capacity per (t,b); overflow prob ~0 for U(0,1) data
#define LPB 16       // lanes (batches) per sim block
#define SDEPTH 513   // per-lane stack capacity / LDS stride (513 % 32 == 1)

__launch_bounds__(64, 1)
__global__ void sim_kernel(const float* __restrict__ u,
                           const float* __restrict__ d,
                           float2* __restrict__ list,
                           int* __restrict__ counts) {
  const int lane = threadIdx.x;
  const int b = blockIdx.x * LPB + lane;
  const bool act = lane < LPB;

  __shared__ float ss[LPB][SDEPTH];             // strengths, compact bottom-up
  __shared__ unsigned short si[LPB][SDEPTH + 3]; // timestep of each entry

  int sp = 0;
  float ut = 0.f, dt = 0.f;
  if (act) { ut = u[b]; dt = d[b]; }

  for (int t = 0; t < TT; ++t) {
    const float cut = ut;
    const float cdt = dt;
    const int tn = (t + 1 < TT) ? (t + 1) : t;
    if (act) {
      ut = u[tn * BB + b];   // prefetch next step early
      dt = d[tn * BB + b];
    }
    if (act) {
      const int base = (t * BB + b) * K;
      int n = 0;

      // ---- load top-W window (independent, batched LDS reads) ----
      const int spw = sp < W ? sp : W;
      float w[W]; int wi[W];
#pragma unroll
      for (int j = 0; j < W; ++j) {
        int k = sp - 1 - j;
        int kk = k < 0 ? 0 : k;
        float sv = ss[lane][kk];
        int iv = si[lane][kk];
        w[j]  = (j < spw) ? sv : 0.f;
        wi[j] = (j < spw) ? iv : 0;
      }

      // ---- pop phase: prefix-scan form of the reversed relu recurrence ----
      float P = 0.f;
#pragma unroll
      for (int j = 0; j < W; ++j) {
        float wt = cut - P;
        P += w[j];
        float sn = w[j] - fmaxf(wt, 0.f);
        w[j] = fmaxf(sn, 0.f);
      }

      if (P < cut && sp > W) {
        // ---- rare slow path: pop reaches below window; full serial step ----
        float cum = 0.f; int newsp = sp;
        for (int k = sp - 1; k >= 0; --k) {
          float wt = cut - cum;
          if (wt <= 0.f) break;
          float so = ss[lane][k]; cum += so;
          float sn = so - wt;
          if (sn <= 0.f) newsp = k;
          else { ss[lane][k] = sn; break; }
        }
        sp = newsp;
        ss[lane][sp] = cdt; si[lane][sp] = (unsigned short)t; sp++;
        float C = 0.f;
        for (int k = sp - 1; k >= 0 && n < K; --k) {
          float rem = 1.f - C;
          if (rem <= 0.f) break;
          float s = ss[lane][k];
          float c = fminf(s, rem);
          if (c > 0.f) {
            list[base + n] = make_float2(c, __int_as_float((int)si[lane][k]));
            n++;
          }
          C += s;
        }
      } else {
        // ---- fast path ----
        int nz = W;
#pragma unroll
        for (int j = W - 1; j >= 0; --j) if (w[j] > 0.f) nz = j;
        int npop = nz < spw ? nz : spw;
#pragma unroll
        for (int j = 0; j < W; ++j) {
          if (j < spw) ss[lane][sp - 1 - j] = w[j];
        }
        const int spo = sp;
        sp -= npop;
        ss[lane][sp] = cdt; si[lane][sp] = (unsigned short)t; sp++;

        // read phase: emit coeffs top-down until cumulative >= 1
        float C = cdt;
        if (cdt > 0.f) {
          list[base + n] = make_float2(fminf(cdt, 1.f), __int_as_float(t));
          n++;
        }
#pragma unroll
        for (int j = 0; j < W; ++j) {
          float rem = 1.f - C;
          float c = fminf(w[j], fmaxf(rem, 0.f));
          if (c > 0.f && n < K) {
            list[base + n] = make_float2(c, __int_as_float(wi[j]));
            n++;
          }
          C += w[j];
        }
        if (C < 1.f) {
          // tail below the window (rare): serial LDS walk
          for (int k = spo - 1 - W; k >= 0 && n < K; --k) {
            float rem = 1.f - C;
            if (rem <= 0.f) break;
            float s = ss[lane][k];
            float c = fminf(s, rem);
            if (c > 0.f) {
              list[base + n] = make_float2(c, __int_as_float((int)si[lane][k]));
              n++;
            }
            C += s;
          }
        }
      }
      counts[t * BB + b] = n;
    }
  }
}

__launch_bounds__(256, 4)
__global__ void read_kernel(const float* __restrict__ v,
                            const float2* __restrict__ list,
                            const int* __restrict__ counts,
                            float* __restrict__ out) {
  const int wid = (int)((blockIdx.x * 256 + threadIdx.x) >> 6); // (t,b) flat
  const int lane = threadIdx.x & 63;
  const int b = wid & (BB - 1);
  const int n = counts[wid];
  const float* vb = v + b * EE;
  const float2* lp = list + (size_t)wid * K;
  float4 r; r.x = 0.f; r.y = 0.f; r.z = 0.f; r.w = 0.f;
  for (int k = 0; k < n; ++k) {
    float2 e = lp[k];                         // uniform broadcast load
    int idx = __float_as_int(e.y);
    float4 x = ((const float4*)(vb + (size_t)idx * (BB * EE)))[lane];
    r.x += e.x * x.x; r.y += e.x * x.y; r.z += e.x * x.z; r.w += e.x * x.w;
  }
  ((float4*)(out + (size_t)wid * EE))[lane] = r;
}

extern "C" void kernel_launch(void* const* d_in, const int* in_sizes, int n_in,
                              void* d_out, int out_size, void* d_ws, size_t ws_size,
                              hipStream_t stream) {
  const float* v = (const float*)d_in[0];
  const float* u = (const float*)d_in[1];
  const float* dd = (const float*)d_in[2];
  float* out = (float*)d_out;
  (void)in_sizes; (void)n_in; (void)out_size; (void)ws_size;

  float2* list = (float2*)d_ws;                       // TT*BB*K*8 = 16.8 MB
  int* counts = (int*)((char*)d_ws + (size_t)TT * BB * K * sizeof(float2));

  hipLaunchKernelGGL(sim_kernel, dim3(BB / LPB), dim3(64), 0, stream,
                     u, dd, list, counts);
  hipLaunchKernelGGL(read_kernel, dim3(TT * BB * 64 / 256), dim3(256), 0, stream,
                     v, list, counts, out);
}

// Round 3
// 574.312 us; speedup vs baseline: 1.6062x; 1.6062x over previous
//
#include <hip/hip_runtime.h>

// Neural stack via exact closed form — no sequential recurrence.
//
// Drains eat the stack from the top; pushes add on top. Entry pushed at step j
// (strength d_j) retains, after step t:
//   s_j^(t) = relu(d_j - relu(max_{j<tau<=t} G_tau - H_j))
//   G_tau = U_tau - Dp_{tau-1},  H_j = U_j - Dp_j   (U,Dp prefix sums of u,d)
// ("dig depth" of drain tau below entry j's top is cumulative-u minus
//  cumulative-d of the entries above; max over tau = total erosion; over-drain
//  waste only happens when the whole stack empties, where all entries are dead
//  anyway, so the overestimate is harmless).
// Read coeffs: walk j = t..0, coeff_j = min(s_j, relu(1 - C)), C += s_j,
// exact early-exit at C >= 1 (reference coeffs are exactly 0 beyond).
//
// Kernel 1: per-batch prefix scans (double accum, float store, [t][b] layout
//           so both its stores and the staging reads stay coalesced/L2-hot).
// Kernel 2: one wave per (t,b) row — uniform register/LDS-broadcast walk +
//           float4 v-gather + coalesced 1KB store. 65536 independent rows.

#define TT 512
#define BB 128
#define EE 256

__launch_bounds__(64, 1)
__global__ void scan_kernel(const float* __restrict__ u,
                            const float* __restrict__ d,
                            float* __restrict__ Gt,   // [TT][BB]
                            float* __restrict__ Ht) { // [TT][BB]
  const int b = blockIdx.x * 64 + threadIdx.x;
  double U = 0.0, D = 0.0;
#pragma unroll 4
  for (int t = 0; t < TT; ++t) {
    float uv = u[t * BB + b];
    float dv = d[t * BB + b];
    U += (double)uv;
    Gt[t * BB + b] = (float)(U - D);   // G_t = U_t - Dp_{t-1}
    D += (double)dv;
    Ht[t * BB + b] = (float)(U - D);   // H_t = U_t - Dp_t
  }
}

__launch_bounds__(256)
__global__ void read_kernel(const float* __restrict__ v,
                            const float* __restrict__ d,
                            const float* __restrict__ Gt,
                            const float* __restrict__ Ht,
                            float* __restrict__ out) {
  const int b = blockIdx.x & (BB - 1);     // low bits: co-scheduled blocks share
  const int chunk = blockIdx.x >> 7;       // the same t-range -> v reuse in L2
  __shared__ float sG[TT], sH[TT], sd[TT];
  for (int i = threadIdx.x; i < TT; i += 256) {
    sG[i] = Gt[i * BB + b];
    sH[i] = Ht[i * BB + b];
    sd[i] = d[i * BB + b];
  }
  __syncthreads();

  const int wave = threadIdx.x >> 6;
  const int lane = threadIdx.x & 63;
  const float4* vb = (const float4*)(v + b * EE);

  for (int r = 0; r < 8; ++r) {
    const int t = chunk * 32 + wave * 8 + r;

    // top entry: s_t = d_t, used-above = 0 -> coeff = min(d_t, 1)
    float dt = sd[t];
    float C = dt;
    float c0 = fminf(dt, 1.f);
    float4 x = vb[(size_t)t * (BB * EE / 4) + lane];
    float4 acc;
    acc.x = c0 * x.x; acc.y = c0 * x.y; acc.z = c0 * x.z; acc.w = c0 * x.w;

    float M = sG[t];                       // max_{j<tau<=t} G_tau, grown as j--
    for (int j = t - 1; j >= 0; --j) {
      if (C >= 1.f) break;                 // all remaining coeffs exactly 0
      float s = fmaxf(sd[j] - fmaxf(M - sH[j], 0.f), 0.f);
      float coef = fminf(s, 1.f - C);      // C<1 here, so relu(1-C)=1-C
      if (coef > 0.f) {                    // wave-uniform branch
        float4 y = vb[(size_t)j * (BB * EE / 4) + lane];
        acc.x += coef * y.x; acc.y += coef * y.y;
        acc.z += coef * y.z; acc.w += coef * y.w;
      }
      C += s;
      M = fmaxf(M, sG[j]);
    }

    float4* op = (float4*)(out + ((size_t)t * BB + b) * EE);
    op[lane] = acc;
  }
}

extern "C" void kernel_launch(void* const* d_in, const int* in_sizes, int n_in,
                              void* d_out, int out_size, void* d_ws, size_t ws_size,
                              hipStream_t stream) {
  const float* v = (const float*)d_in[0];
  const float* u = (const float*)d_in[1];
  const float* dd = (const float*)d_in[2];
  float* out = (float*)d_out;
  (void)in_sizes; (void)n_in; (void)out_size; (void)ws_size;

  float* Gt = (float*)d_ws;                          // [TT][BB] = 256 KB
  float* Ht = Gt + (size_t)TT * BB;                  // [TT][BB] = 256 KB

  hipLaunchKernelGGL(scan_kernel, dim3(BB / 64), dim3(64), 0, stream,
                     u, dd, Gt, Ht);
  hipLaunchKernelGGL(read_kernel, dim3((TT / 32) * BB), dim3(256), 0, stream,
                     v, dd, Gt, Ht, out);
}

// Round 5
// 158.881 us; speedup vs baseline: 5.8058x; 3.6147x over previous
//
#include <hip/hip_runtime.h>

// Neural stack, closed form, SINGLE self-contained kernel (no d_ws — round 4's
// two-kernel d_ws handoff produced correct first-call output but diverged
// under graph replay; everything is now recomputed from d_in per block).
//
// s_j^(t) = relu(d_j - relu(max_{j<tau<=t} G_tau - H_j)),
//   G_tau = U_tau - Dp_{tau-1}, H_j = U_j - Dp_j  (prefix sums of u, d).
// Per row t: p = t - j, M = exclusive prefix-MAX of G (p-order), C = exclusive
// prefix-SUM of s, coeff = min(s, relu(1-C)); exactly 0 once C >= 1.
// Each 64-lane chunk is processed in parallel: shuffle max-scan -> s ->
// shuffle sum-scan -> ballot -> broadcast-gather contributing v rows.
//
// Block (chunk,b): stage u,d for batch b into LDS; wave 0 computes G,H via
// shuffle double-scan; all 4 waves then produce 8 rows each.

#define TT 512
#define BB 128
#define EE 256

__launch_bounds__(256)
__global__ void stack_kernel(const float* __restrict__ v,
                             const float* __restrict__ u,
                             const float* __restrict__ d,
                             float* __restrict__ out) {
  const int b = blockIdx.x & (BB - 1);
  const int chunk = blockIdx.x >> 7;
  const int tmax = chunk * 32 + 31;
  const int nload = tmax + 1;

  __shared__ float sU[TT], sG[TT], sH[TT], sd[TT];

  // ---- stage u,d for this batch (L2-hot: u,d are 256 KB each) ----
  for (int i = threadIdx.x; i < nload; i += 256) {
    sU[i] = u[i * BB + b];
    sd[i] = d[i * BB + b];
  }
  __syncthreads();

  // ---- wave 0: double-precision inclusive scans -> G,H in LDS ----
  if (threadIdx.x < 64) {
    const int lane = threadIdx.x;
    double cU = 0.0, cD = 0.0;
    for (int base = 0; base < nload; base += 64) {
      const int i = base + lane;
      double uv = (i < nload) ? (double)sU[i] : 0.0;
      double dv = (i < nload) ? (double)sd[i] : 0.0;
      double su = uv, sdv = dv;
#pragma unroll
      for (int o = 1; o < 64; o <<= 1) {
        double yu = __shfl_up(su, o);
        double yd = __shfl_up(sdv, o);
        if (lane >= o) { su += yu; sdv += yd; }
      }
      double U = cU + su;
      double D = cD + sdv;
      if (i < nload) {
        sG[i] = (float)(U - (D - dv));   // G_t = U_t - Dp_{t-1}
        sH[i] = (float)(U - D);          // H_t = U_t - Dp_t
      }
      cU += __shfl(su, 63);
      cD += __shfl(sdv, 63);
    }
  }
  __syncthreads();

  // ---- walk: 4 waves x 8 rows ----
  const int wave = threadIdx.x >> 6;
  const int lane = threadIdx.x & 63;
  const float4* vb = (const float4*)(v + b * EE);
  const int VSTRIDE = BB * EE / 4;   // float4 stride between t-rows of v

  for (int r = 0; r < 8; ++r) {
    const int t = chunk * 32 + wave * 8 + r;
    float4 acc; acc.x = 0.f; acc.y = 0.f; acc.z = 0.f; acc.w = 0.f;
    float Ccarry = 0.f;
    float Mcarry = -3e38f;

    for (int base = 0; base <= t; base += 64) {
      const int p = base + lane;           // position from top (p=0 -> j=t)
      const int j = t - p;
      float Gv, Hv, dv;
      if (p <= t) { Gv = sG[j]; Hv = sH[j]; dv = sd[j]; }
      else        { Gv = -3e38f; Hv = 0.f; dv = 0.f; }

      // inclusive max-scan of G in p-order
      float gmax = Gv;
#pragma unroll
      for (int o = 1; o < 64; o <<= 1) {
        float y = __shfl_up(gmax, o);
        if (lane >= o) gmax = fmaxf(gmax, y);
      }
      float Mex = __shfl_up(gmax, 1);
      Mex = (lane == 0) ? Mcarry : fmaxf(Mex, Mcarry);

      float s = fmaxf(dv - fmaxf(Mex - Hv, 0.f), 0.f);

      // inclusive sum-scan of s in p-order
      float csum = s;
#pragma unroll
      for (int o = 1; o < 64; o <<= 1) {
        float y = __shfl_up(csum, o);
        if (lane >= o) csum += y;
      }
      float Cex = __shfl_up(csum, 1);
      Cex = (lane == 0) ? Ccarry : (Cex + Ccarry);

      float coeff = fminf(s, fmaxf(1.f - Cex, 0.f));

      unsigned long long m = __ballot(coeff > 0.f);
      while (m) {
        int l = __ffsll((unsigned long long)m) - 1;
        m &= m - 1;
        float c  = __shfl(coeff, l);
        int   jj = __shfl(j, l);
        float4 y = vb[(size_t)jj * VSTRIDE + lane];
        acc.x += c * y.x; acc.y += c * y.y; acc.z += c * y.z; acc.w += c * y.w;
      }

      Ccarry = Ccarry + __shfl(csum, 63);
      Mcarry = fmaxf(Mcarry, __shfl(gmax, 63));
      if (Ccarry >= 1.f) break;            // all deeper coeffs exactly 0
    }

    ((float4*)(out + ((size_t)t * BB + b) * EE))[lane] = acc;
  }
}

extern "C" void kernel_launch(void* const* d_in, const int* in_sizes, int n_in,
                              void* d_out, int out_size, void* d_ws, size_t ws_size,
                              hipStream_t stream) {
  const float* v = (const float*)d_in[0];
  const float* u = (const float*)d_in[1];
  const float* dd = (const float*)d_in[2];
  float* out = (float*)d_out;
  (void)in_sizes; (void)n_in; (void)out_size; (void)d_ws; (void)ws_size;

  hipLaunchKernelGGL(stack_kernel, dim3((TT / 32) * BB), dim3(256), 0, stream,
                     v, u, dd, out);
}

// Round 6
// 133.438 us; speedup vs baseline: 6.9129x; 1.1907x over previous
//
#include <hip/hip_runtime.h>

// Neural stack, closed form, single kernel. Round 6: DPP wave scans + striped
// row->block mapping for load balance.
//
// s_j^(t) = relu(d_j - relu(max_{j<tau<=t} G_tau - H_j)),
//   G_tau = U_tau - Dp_{tau-1}, H_j = U_j - Dp_j  (prefix sums of u, d).
// Per row t (p = t - j): M = exclusive prefix-MAX of G, C = exclusive
// prefix-SUM of s, coeff = min(s, relu(1-C)); exactly 0 once C >= 1.
//
// Block (g,b), g in [0,16): rows t = g + 16*(w + 4r) for wave w, iter r —
// every block/wave gets a near-equal mix of shallow and deep rows.
// Scans use gfx9 DPP ladder (row_shr 1/2/4/8, row_bcast 15/31): pure-VALU,
// ~8x lower latency than the round-5 dependent-ds_bpermute shfl chains.

#define TT 512
#define BB 128
#define EE 256

template <int CTRL, int RM>
__device__ __forceinline__ float dppmov(float o, float s) {
  return __int_as_float(__builtin_amdgcn_update_dpp(
      __float_as_int(o), __float_as_int(s), CTRL, RM, 0xf, false));
}

__device__ __forceinline__ float readlanef(float v, int l) {
  return __int_as_float(__builtin_amdgcn_readlane(__float_as_int(v), l));
}

// wave64 inclusive max-scan (identity -inf)
__device__ __forceinline__ float scan_max64(float v) {
  const float NI = -__builtin_inff();
  v = fmaxf(v, dppmov<0x111, 0xf>(NI, v));   // row_shr:1
  v = fmaxf(v, dppmov<0x112, 0xf>(NI, v));   // row_shr:2
  v = fmaxf(v, dppmov<0x114, 0xf>(NI, v));   // row_shr:4
  v = fmaxf(v, dppmov<0x118, 0xf>(NI, v));   // row_shr:8
  v = fmaxf(v, dppmov<0x142, 0xa>(NI, v));   // row_bcast:15 -> rows 1,3
  v = fmaxf(v, dppmov<0x143, 0xc>(NI, v));   // row_bcast:31 -> rows 2,3
  return v;
}

// wave64 inclusive sum-scan (identity 0)
__device__ __forceinline__ float scan_add64(float v) {
  v += dppmov<0x111, 0xf>(0.f, v);
  v += dppmov<0x112, 0xf>(0.f, v);
  v += dppmov<0x114, 0xf>(0.f, v);
  v += dppmov<0x118, 0xf>(0.f, v);
  v += dppmov<0x142, 0xa>(0.f, v);
  v += dppmov<0x143, 0xc>(0.f, v);
  return v;
}

// whole-wave shift right by 1 (lane0 <- carry)
__device__ __forceinline__ float wshr1(float carry, float v) {
  return __int_as_float(__builtin_amdgcn_update_dpp(
      __float_as_int(carry), __float_as_int(v), 0x138, 0xf, 0xf, false));
}

__launch_bounds__(256)
__global__ void stack_kernel(const float* __restrict__ v,
                             const float* __restrict__ u,
                             const float* __restrict__ d,
                             float* __restrict__ out) {
  const int b = blockIdx.x & (BB - 1);
  const int g = blockIdx.x >> 7;            // stripe id, 0..15

  __shared__ float sG[TT], sH[TT], sd[TT];
  __shared__ double sUd[TT], sDd[TT];
  __shared__ double segU[4], segD[4];

  // ---- Phase A: stage u,d (u,d are 256 KB each -> L2-hot) ----
  for (int i = threadIdx.x; i < TT; i += 256) {
    float uv = u[i * BB + b];
    float dv = d[i * BB + b];
    sd[i] = dv;
    sUd[i] = (double)uv;
    sDd[i] = (double)dv;
  }
  __syncthreads();

  const int wave = threadIdx.x >> 6;
  const int lane = threadIdx.x & 63;

  // ---- Phase B: per-wave segmented f64 inclusive scans (128 entries/wave) --
  {
    double cU = 0.0, cD = 0.0;
    const int i0 = wave * 128;
    for (int c = 0; c < 2; ++c) {
      const int i = i0 + c * 64 + lane;
      double su = sUd[i];
      double sv = sDd[i];
#pragma unroll
      for (int o = 1; o < 64; o <<= 1) {
        double yu = __shfl_up(su, o);
        double yv = __shfl_up(sv, o);
        if (lane >= o) { su += yu; sv += yv; }
      }
      sUd[i] = cU + su;
      sDd[i] = cD + sv;
      cU += __shfl(su, 63);
      cD += __shfl(sv, 63);
    }
    if (lane == 0) { segU[wave] = cU; segD[wave] = cD; }
  }
  __syncthreads();

  // ---- Phase C: add segment offsets, emit float G,H ----
  for (int i = threadIdx.x; i < TT; i += 256) {
    const int ws = i >> 7;
    double oU = 0.0, oD = 0.0;
    for (int w2 = 0; w2 < ws; ++w2) { oU += segU[w2]; oD += segD[w2]; }
    double U = sUd[i] + oU;
    double D = sDd[i] + oD;
    float dv = sd[i];
    sG[i] = (float)(U - (D - (double)dv));   // G_t = U_t - Dp_{t-1}
    sH[i] = (float)(U - D);                  // H_t = U_t - Dp_t
  }
  __syncthreads();

  // ---- Phase D: walks. 4 waves x 8 rows, striped over depth ----
  const float4* vb = (const float4*)(v + b * EE);
  const int VSTRIDE = BB * EE / 4;
  const float NI = -__builtin_inff();

  for (int r = 0; r < 8; ++r) {
    const int t = g + 16 * wave + 64 * r;
    float4 acc; acc.x = 0.f; acc.y = 0.f; acc.z = 0.f; acc.w = 0.f;
    float Ccarry = 0.f;
    float Mcarry = NI;

    for (int base = 0; base <= t; base += 64) {
      const int p = base + lane;            // position from top (p=0 -> j=t)
      const int j = t - p;
      const int jc = j < 0 ? 0 : j;
      const bool in = (p <= t);
      float Gv = in ? sG[jc] : NI;
      float Hv = in ? sH[jc] : 0.f;
      float dv = in ? sd[jc] : 0.f;

      float gmax = scan_max64(Gv);                     // inclusive max of G
      float Mex = fmaxf(wshr1(Mcarry, gmax), Mcarry);  // exclusive + carry

      float s = fmaxf(dv - fmaxf(Mex - Hv, 0.f), 0.f);

      float csum = scan_add64(s);                      // inclusive sum of s
      float Cex = wshr1(0.f, csum) + Ccarry;           // exclusive + carry

      float coeff = fminf(s, fmaxf(1.f - Cex, 0.f));

      unsigned long long m = __ballot(coeff > 0.f);
      while (m) {
        int l = __ffsll(m) - 1;
        m &= m - 1;
        float c = readlanef(coeff, l);
        int jj = t - (base + l);
        float4 y = vb[(size_t)jj * VSTRIDE + lane];
        acc.x += c * y.x; acc.y += c * y.y; acc.z += c * y.z; acc.w += c * y.w;
      }

      Ccarry = Ccarry + readlanef(csum, 63);
      Mcarry = fmaxf(Mcarry, readlanef(gmax, 63));
      if (Ccarry >= 1.f) break;            // all deeper coeffs exactly 0
    }

    ((float4*)(out + ((size_t)t * BB + b) * EE))[lane] = acc;
  }
}

extern "C" void kernel_launch(void* const* d_in, const int* in_sizes, int n_in,
                              void* d_out, int out_size, void* d_ws, size_t ws_size,
                              hipStream_t stream) {
  const float* v = (const float*)d_in[0];
  const float* u = (const float*)d_in[1];
  const float* dd = (const float*)d_in[2];
  float* out = (float*)d_out;
  (void)in_sizes; (void)n_in; (void)out_size; (void)d_ws; (void)ws_size;

  hipLaunchKernelGGL(stack_kernel, dim3(16 * BB), dim3(256), 0, stream,
                     v, u, dd, out);
}